// Round 3
// baseline (153.556 us; speedup 1.0000x reference)
//
#include <hip/hip_runtime.h>
#include <stdint.h>

#define NPIX     129600      // 270*480
#define NC       50          // candidates incl. input-mv
#define N2       49          // block-match candidates (7x7)
// float32-element offsets into d_out (outputs concatenated in return order)
#define OUT_TMPL 259200
#define OUT_MASK 2332800
#define OUT_COST 2462400

// rank[flat] = position of flat index (j+3)*7+(i+3) in the center-out spiral.
// Verified by full step-by-step simulation of _spiral_order(3) (round 2).
__constant__ unsigned char RANKLUT[49] = {
  42,43,44,45,46,47,48,
  41,20,21,22,23,24,25,
  40,19, 6, 7, 8, 9,26,
  39,18, 5, 0, 1,10,27,
  38,17, 4, 3, 2,11,28,
  37,16,15,14,13,12,29,
  36,35,34,33,32,31,30
};

__global__ __launch_bounds__(256) void cv_kernel(
    const float* __restrict__ w1,
    const float* __restrict__ w2,
    float* __restrict__ out)
{
  const int wave = threadIdx.x >> 6;
  const int lane = threadIdx.x & 63;
  const int p = blockIdx.x * 4 + wave;   // one wave per pixel; grid*4 == NPIX

  // ---- per-lane candidate SAD: lane c (< 50) owns candidate c.
  // 16 f32 = 64 B per input per lane; lanes 0..49 cover the pixel's 3200 B
  // contiguously -> fully coalesced burst.
  float A[16];
#pragma unroll
  for (int r = 0; r < 16; ++r) A[r] = 0.f;
  int cost = 0;
  if (lane < NC) {
    const float4* pa = (const float4*)(w1 + (size_t)p * (NC * 16) + lane * 16);
    const float4* pb = (const float4*)(w2 + (size_t)p * (NC * 16) + lane * 16);
    float4 a0 = pa[0], a1 = pa[1], a2 = pa[2], a3 = pa[3];
    float4 b0 = pb[0], b1 = pb[1], b2 = pb[2], b3 = pb[3];
    A[0]=a0.x; A[1]=a0.y; A[2]=a0.z; A[3]=a0.w;
    A[4]=a1.x; A[5]=a1.y; A[6]=a1.z; A[7]=a1.w;
    A[8]=a2.x; A[9]=a2.y; A[10]=a2.z; A[11]=a2.w;
    A[12]=a3.x; A[13]=a3.y; A[14]=a3.z; A[15]=a3.w;
    float B[16] = {b0.x,b0.y,b0.z,b0.w, b1.x,b1.y,b1.z,b1.w,
                   b2.x,b2.y,b2.z,b2.w, b3.x,b3.y,b3.z,b3.w};
    float s = 0.f;
#pragma unroll
    for (int r = 0; r < 16; ++r) s += fabsf(A[r] - B[r]);
    cost = (int)s;   // exact: integer sum <= 16*255 = 4080
  }

  // ---- spiral-first argmin over lanes 0..48 via packed key min-reduction
  // key = cost(12b) | spiral_rank(6b) | flat_idx(6b)  -> lexicographic
  // (min cost, then min spiral rank), carrying the flat index out for free.
  int key = (lane < N2) ? ((cost << 12) | ((int)RANKLUT[lane] << 6) | lane)
                        : 0x7FFFFFFF;
#pragma unroll
  for (int m = 32; m >= 1; m >>= 1) {
    int o = __shfl_xor(key, m, 64);
    key = min(key, o);
  }
  const int cost49   = __shfl(cost, N2, 64);   // input-mv candidate cost
  const int flat_bm  = key & 63;
  const int cost_bm  = key >> 12;
  const bool mv      = cost49 < cost_bm;       // strict, per reference
  const int min_cost = mv ? cost49 : cost_bm;
  const int min_idx  = mv ? N2 : flat_bm;      // templates use min_idx (may be 49)

  // winning lane already holds w1[p, min_idx, 0..15] in registers -> shuffle out
  float t[16];
#pragma unroll
  for (int r = 0; r < 16; ++r) t[r] = __shfl(A[r], min_idx, 64);

  if (lane == 0) {
    // min_templates: 16 f32 = 64 B, 16B-aligned ((259200 + p*16)*4 % 16 == 0)
    float4* tp = (float4*)(out + OUT_TMPL + (size_t)p * 16);
    tp[0] = make_float4(t[0],  t[1],  t[2],  t[3]);
    tp[1] = make_float4(t[4],  t[5],  t[6],  t[7]);
    tp[2] = make_float4(t[8],  t[9],  t[10], t[11]);
    tp[3] = make_float4(t[12], t[13], t[14], t[15]);
    // vector = VEC_LUT[min_idx_bm] = (-j, -i); uses block-match index only
    const int jj = flat_bm / 7 - 3;
    const int ii = flat_bm % 7 - 3;
    *(float2*)(out + (size_t)p * 2) = make_float2((float)(-jj), (float)(-ii));
    // input_mv_mask (bool -> 1.0/0.0), min_cost_volume (int -> f32, exact)
    out[OUT_MASK + p] = mv ? 1.0f : 0.0f;
    out[OUT_COST + p] = (float)min_cost;
  }
}

extern "C" void kernel_launch(void* const* d_in, const int* in_sizes, int n_in,
                              void* d_out, int out_size, void* d_ws, size_t ws_size,
                              hipStream_t stream) {
  const float* w1 = (const float*)d_in[0];
  const float* w2 = (const float*)d_in[1];
  float* out = (float*)d_out;
  dim3 grid(NPIX / 4);   // 32400 blocks, 4 waves (pixels) per block
  dim3 block(256);
  cv_kernel<<<grid, block, 0, stream>>>(w1, w2, out);
}